// Round 2
// 288.953 us; speedup vs baseline: 1.0448x; 1.0448x over previous
//
#include <hip/hip_runtime.h>
#include <cstdint>
#include <cstddef>

#define LOG_ALPHA -2.302585092994046f  // ln(0.1)
#define ALPHA 0.1f

typedef float nfloat4 __attribute__((ext_vector_type(4)));  // clang-native for nontemporal

// Stage 1: per-(row-chunk, column) partial stats — NO atomics, no pre-zero.
// For column j, row-chunk by:
//   partials[by][0][j] = sum_{r in chunk} v_r * relu(t),  t = u*x[r,j] + a
//   partials[by][1][j] = sum_{r in chunk, t>0} v_r
//   partials[by][2][j] = sum_{r in chunk} w_r * relu(t)
//   partials[by][3][j] = sum_{r in chunk, t>0} w_r
// Each thread owns 4 consecutive columns (float4 loads/stores, fully coalesced).
__global__ __launch_bounds__(256) void col_stats_kernel(
    const float* __restrict__ x, const float* __restrict__ w,
    const float* __restrict__ v, const float* __restrict__ up,
    const float* __restrict__ ap, float* __restrict__ partials,
    int DIM, int RPB) {
  const int q = blockIdx.x * blockDim.x + threadIdx.x;  // column quad
  const int by = blockIdx.y;
  const int r0 = by * RPB;
  const float u = up[0], a = ap[0];
  const float4* x4 = (const float4*)x;
  const int ld4 = DIM >> 2;
  float4 fv = {0, 0, 0, 0}, dv = {0, 0, 0, 0};
  float4 fw = {0, 0, 0, 0}, dw = {0, 0, 0, 0};
#pragma unroll 4
  for (int r = r0; r < r0 + RPB; ++r) {
    float4 xv = x4[(size_t)r * ld4 + q];  // 16 B/lane, coalesced
    float vb = v[r], wb = w[r];           // wave-uniform -> s_load
    float t, rt, m;
    t = fmaf(u, xv.x, a); rt = fmaxf(t, 0.f); m = t > 0.f ? 1.f : 0.f;
    fv.x = fmaf(vb, rt, fv.x); dv.x = fmaf(vb, m, dv.x);
    fw.x = fmaf(wb, rt, fw.x); dw.x = fmaf(wb, m, dw.x);
    t = fmaf(u, xv.y, a); rt = fmaxf(t, 0.f); m = t > 0.f ? 1.f : 0.f;
    fv.y = fmaf(vb, rt, fv.y); dv.y = fmaf(vb, m, dv.y);
    fw.y = fmaf(wb, rt, fw.y); dw.y = fmaf(wb, m, dw.y);
    t = fmaf(u, xv.z, a); rt = fmaxf(t, 0.f); m = t > 0.f ? 1.f : 0.f;
    fv.z = fmaf(vb, rt, fv.z); dv.z = fmaf(vb, m, dv.z);
    fw.z = fmaf(wb, rt, fw.z); dw.z = fmaf(wb, m, dw.z);
    t = fmaf(u, xv.w, a); rt = fmaxf(t, 0.f); m = t > 0.f ? 1.f : 0.f;
    fv.w = fmaf(vb, rt, fv.w); dv.w = fmaf(vb, m, dv.w);
    fw.w = fmaf(wb, rt, fw.w); dw.w = fmaf(wb, m, dw.w);
  }
  // Coalesced float4 partial writes: 4 stores/thread, no contention.
  ((float4*)(partials + ((size_t)by * 4 + 0) * DIM))[q] = fv;
  ((float4*)(partials + ((size_t)by * 4 + 1) * DIM))[q] = dv;
  ((float4*)(partials + ((size_t)by * 4 + 2) * DIM))[q] = fw;
  ((float4*)(partials + ((size_t)by * 4 + 3) * DIM))[q] = dw;
}

// Stage 2: fold NBY row-chunk partials per (array, column).
// red[arr][col] = sum_by partials[by][arr][col]. One thread per (arr,col):
// consecutive threads read consecutive floats -> 256 B/wave, coalesced.
__global__ __launch_bounds__(256) void reduce_kernel(
    const float* __restrict__ partials, float* __restrict__ red,
    int DIM, int NBY) {
  const int idx = blockIdx.x * blockDim.x + threadIdx.x;  // [0, 4*DIM)
  const int arr = idx / DIM;
  const int col = idx - arr * DIM;
  const float* p = partials + (size_t)arr * DIM + col;
  const size_t stride = (size_t)4 * DIM;
  float acc = 0.f;
#pragma unroll 8
  for (int by = 0; by < NBY; ++by) acc += p[(size_t)by * stride];
  red[idx] = acc;
}

// Single-wave affine scan: d_{i+1} = F0v[i] + Dv[i]*d_i, d_0 = 0, then
// e_{i+1} = F0w[i] + Dw[i]*d_i during replay. e_0 = 0.
__global__ void scan_kernel(const float* __restrict__ F0v,
                            const float* __restrict__ Dv,
                            const float* __restrict__ F0w,
                            const float* __restrict__ Dw,
                            float* __restrict__ e, int DIM) {
  const int L = threadIdx.x;  // one wave: 64 lanes
  const int S = DIM >> 6;     // segment length per lane
  const int base = L * S;     // lane L consumes indices [base, base+S)
  const float4* F4 = (const float4*)F0v;
  const float4* D4 = (const float4*)Dv;
  const float4* Fw4 = (const float4*)F0w;
  const float4* Dw4 = (const float4*)Dw;
  const int q0 = base >> 2, nq = S >> 2;
  // Phase 1: compose my segment's affine map p -> B + A*p (vectorized loads)
  float A = 1.f, B = 0.f;
#pragma unroll 4
  for (int qq = 0; qq < nq; ++qq) {
    float4 f = F4[q0 + qq], dd = D4[q0 + qq];
    B = fmaf(dd.x, B, f.x); A *= dd.x;
    B = fmaf(dd.y, B, f.y); A *= dd.y;
    B = fmaf(dd.z, B, f.z); A *= dd.z;
    B = fmaf(dd.w, B, f.w); A *= dd.w;
  }
  // Inclusive composition scan across lanes
  for (int off = 1; off < 64; off <<= 1) {
    float Ao = __shfl_up(A, off, 64);
    float Bo = __shfl_up(B, off, 64);
    if (L >= off) { B = fmaf(A, Bo, B); A = A * Ao; }
  }
  float d = __shfl_up(B, 1, 64);  // d at my segment start
  if (L == 0) d = 0.f;
  // Phase 2: replay, emitting e_{j+1} = F0w[j] + Dw[j]*d_j
  // (entering element j: d == d_j; emit e BEFORE advancing d — order verified)
  if (L == 0) e[0] = 0.f;
#pragma unroll 4
  for (int qq = 0; qq < nq; ++qq) {
    float4 f = F4[q0 + qq], dd = D4[q0 + qq];
    float4 fw = Fw4[q0 + qq], dwv = Dw4[q0 + qq];
    int j = base + (qq << 2);
    if (j + 1 < DIM) e[j + 1] = fmaf(dwv.x, d, fw.x);
    d = fmaf(dd.x, d, f.x);
    if (j + 2 < DIM) e[j + 2] = fmaf(dwv.y, d, fw.y);
    d = fmaf(dd.y, d, f.y);
    if (j + 3 < DIM) e[j + 3] = fmaf(dwv.z, d, fw.z);
    d = fmaf(dd.z, d, f.z);
    if (j + 4 < DIM) e[j + 4] = fmaf(dwv.w, d, fw.w);
    d = fmaf(dd.w, d, f.w);
  }
}

// z[b,i] = leakyrelu(y*x[b,i] + e_i + b0); ld[b] = DIM*log|y| + cnt_neg*ln(alpha)
// z is written once and never re-read: stream it with non-temporal stores so
// it does not evict x (134 MB) from Infinity Cache during the second x pass.
__global__ __launch_bounds__(256) void z_kernel(
    const float* __restrict__ x, const float* __restrict__ e,
    const float* __restrict__ yp, const float* __restrict__ bp,
    float* __restrict__ z, float* __restrict__ ld, int DIM) {
  const int row = blockIdx.x;
  const int tx = threadIdx.x;
  const float y = yp[0], b0 = bp[0];
  const float4* xr = (const float4*)(x + (size_t)row * DIM);
  const float4* er = (const float4*)e;
  nfloat4* zr = (nfloat4*)(z + (size_t)row * DIM);
  int cnt = 0;
  const int n4 = DIM >> 2;
  for (int k = tx; k < n4; k += blockDim.x) {
    float4 xv = xr[k], ev = er[k];
    nfloat4 zv;
    float lin;
    lin = fmaf(y, xv.x, ev.x + b0); zv.x = lin >= 0.f ? lin : ALPHA * lin; cnt += (lin < 0.f);
    lin = fmaf(y, xv.y, ev.y + b0); zv.y = lin >= 0.f ? lin : ALPHA * lin; cnt += (lin < 0.f);
    lin = fmaf(y, xv.z, ev.z + b0); zv.z = lin >= 0.f ? lin : ALPHA * lin; cnt += (lin < 0.f);
    lin = fmaf(y, xv.w, ev.w + b0); zv.w = lin >= 0.f ? lin : ALPHA * lin; cnt += (lin < 0.f);
    __builtin_nontemporal_store(zv, &zr[k]);
  }
  for (int off = 32; off > 0; off >>= 1) cnt += __shfl_down(cnt, off, 64);
  __shared__ int wc[4];
  int wid = tx >> 6, lane = tx & 63;
  if (lane == 0) wc[wid] = cnt;
  __syncthreads();
  if (tx == 0) {
    int total = wc[0] + wc[1] + wc[2] + wc[3];
    ld[row] = (float)DIM * logf(fabsf(y)) + (float)total * LOG_ALPHA;
  }
}

extern "C" void kernel_launch(void* const* d_in, const int* in_sizes, int n_in,
                              void* d_out, int out_size, void* d_ws, size_t ws_size,
                              hipStream_t stream) {
  const float* x = (const float*)d_in[0];
  const float* y = (const float*)d_in[1];
  const float* w = (const float*)d_in[2];
  const float* b = (const float*)d_in[3];
  const float* u = (const float*)d_in[4];
  const float* v = (const float*)d_in[5];
  const float* a = (const float*)d_in[6];
  const int HID = in_sizes[2];         // w has HID elements
  const int DIM = in_sizes[0] / HID;   // x is [HID, DIM]

  const int RPB = 32;                  // rows per chunk (4 blocks/CU occupancy)
  const int NBY = HID / RPB;           // 256 row-chunks

  float* ws = (float*)d_ws;
  float* partials = ws;                              // NBY*4*DIM floats (16 MB)
  float* red = ws + (size_t)NBY * 4 * DIM;           // 4*DIM reduced stats
  float* F0v = red;           float* Dv = red + DIM;
  float* F0w = red + 2 * DIM; float* Dw = red + 3 * DIM;
  float* e = red + (size_t)4 * DIM;                  // DIM scan outputs

  float* z = (float*)d_out;
  float* ld = z + (size_t)HID * DIM;

  // Stage 1: partial stats, atomic-free (no zeroing needed — fully overwritten)
  dim3 grid1(DIM / (256 * 4), NBY);
  col_stats_kernel<<<grid1, 256, 0, stream>>>(x, w, v, u, a, partials, DIM, RPB);
  // Stage 2: fold partials -> F0v/Dv/F0w/Dw
  reduce_kernel<<<(4 * DIM) / 256, 256, 0, stream>>>(partials, red, DIM, NBY);
  // Stage 3: sequential affine scan (single wave)
  scan_kernel<<<1, 64, 0, stream>>>(F0v, Dv, F0w, Dw, e, DIM);
  // Stage 4: elementwise z + log-det count
  z_kernel<<<HID, 256, 0, stream>>>(x, e, y, b, z, ld, DIM);
}

// Round 3
// 280.852 us; speedup vs baseline: 1.0750x; 1.0288x over previous
//
#include <hip/hip_runtime.h>
#include <cstdint>
#include <cstddef>

#define LOG_ALPHA -2.302585092994046f  // ln(0.1)
#define ALPHA 0.1f

typedef float nfloat4 __attribute__((ext_vector_type(4)));  // clang-native vector (nontemporal-capable)

// Stage 1: per-(row-chunk, column) partial stats — NO atomics, no pre-zero.
// For column j, row-chunk by:
//   partials[by][0][j] = sum_{r in chunk} v_r * relu(t),  t = u*x[r,j] + a
//   partials[by][1][j] = sum_{r in chunk, t>0} v_r
//   partials[by][2][j] = sum_{r in chunk} w_r * relu(t)
//   partials[by][3][j] = sum_{r in chunk, t>0} w_r
// Each thread owns 4 consecutive columns (float4 loads/stores, fully coalesced).
__global__ __launch_bounds__(256) void col_stats_kernel(
    const float* __restrict__ x, const float* __restrict__ w,
    const float* __restrict__ v, const float* __restrict__ up,
    const float* __restrict__ ap, float* __restrict__ partials,
    int DIM, int RPB) {
  const int q = blockIdx.x * blockDim.x + threadIdx.x;  // column quad
  const int by = blockIdx.y;
  const int r0 = by * RPB;
  const float u = up[0], a = ap[0];
  const float4* x4 = (const float4*)x;
  const int ld4 = DIM >> 2;
  float4 fv = {0, 0, 0, 0}, dv = {0, 0, 0, 0};
  float4 fw = {0, 0, 0, 0}, dw = {0, 0, 0, 0};
#pragma unroll 4
  for (int r = r0; r < r0 + RPB; ++r) {
    float4 xv = x4[(size_t)r * ld4 + q];  // 16 B/lane, coalesced
    float vb = v[r], wb = w[r];           // wave-uniform -> s_load
    float t, rt, m;
    t = fmaf(u, xv.x, a); rt = fmaxf(t, 0.f); m = t > 0.f ? 1.f : 0.f;
    fv.x = fmaf(vb, rt, fv.x); dv.x = fmaf(vb, m, dv.x);
    fw.x = fmaf(wb, rt, fw.x); dw.x = fmaf(wb, m, dw.x);
    t = fmaf(u, xv.y, a); rt = fmaxf(t, 0.f); m = t > 0.f ? 1.f : 0.f;
    fv.y = fmaf(vb, rt, fv.y); dv.y = fmaf(vb, m, dv.y);
    fw.y = fmaf(wb, rt, fw.y); dw.y = fmaf(wb, m, dw.y);
    t = fmaf(u, xv.z, a); rt = fmaxf(t, 0.f); m = t > 0.f ? 1.f : 0.f;
    fv.z = fmaf(vb, rt, fv.z); dv.z = fmaf(vb, m, dv.z);
    fw.z = fmaf(wb, rt, fw.z); dw.z = fmaf(wb, m, dw.z);
    t = fmaf(u, xv.w, a); rt = fmaxf(t, 0.f); m = t > 0.f ? 1.f : 0.f;
    fv.w = fmaf(vb, rt, fv.w); dv.w = fmaf(vb, m, dv.w);
    fw.w = fmaf(wb, rt, fw.w); dw.w = fmaf(wb, m, dw.w);
  }
  // Coalesced float4 partial writes: 4 stores/thread, no contention.
  ((float4*)(partials + ((size_t)by * 4 + 0) * DIM))[q] = fv;
  ((float4*)(partials + ((size_t)by * 4 + 1) * DIM))[q] = dv;
  ((float4*)(partials + ((size_t)by * 4 + 2) * DIM))[q] = fw;
  ((float4*)(partials + ((size_t)by * 4 + 3) * DIM))[q] = dw;
}

// Stage 2: fold NBY row-chunk partials per (array, column).
// red[arr][col] = sum_by partials[by][arr][col]. One thread per (arr,col):
// consecutive threads read consecutive floats -> coalesced. Partials are read
// exactly once -> non-temporal loads (don't pollute L2/L3; keep x resident).
__global__ __launch_bounds__(256) void reduce_kernel(
    const float* __restrict__ partials, float* __restrict__ red,
    int DIM, int NBY) {
  const int idx = blockIdx.x * blockDim.x + threadIdx.x;  // [0, 4*DIM)
  const int arr = idx / DIM;
  const int col = idx - arr * DIM;
  const float* p = partials + (size_t)arr * DIM + col;
  const size_t stride = (size_t)4 * DIM;
  float acc = 0.f;
#pragma unroll 8
  for (int by = 0; by < NBY; ++by)
    acc += __builtin_nontemporal_load(p + (size_t)by * stride);
  red[idx] = acc;
}

// Single-wave affine scan: d_{i+1} = F0v[i] + Dv[i]*d_i, d_0 = 0, then
// e_{i+1} = F0w[i] + Dw[i]*d_i during replay. e_0 = 0.
__global__ void scan_kernel(const float* __restrict__ F0v,
                            const float* __restrict__ Dv,
                            const float* __restrict__ F0w,
                            const float* __restrict__ Dw,
                            float* __restrict__ e, int DIM) {
  const int L = threadIdx.x;  // one wave: 64 lanes
  const int S = DIM >> 6;     // segment length per lane
  const int base = L * S;     // lane L consumes indices [base, base+S)
  const float4* F4 = (const float4*)F0v;
  const float4* D4 = (const float4*)Dv;
  const float4* Fw4 = (const float4*)F0w;
  const float4* Dw4 = (const float4*)Dw;
  const int q0 = base >> 2, nq = S >> 2;
  // Phase 1: compose my segment's affine map p -> B + A*p (vectorized loads)
  float A = 1.f, B = 0.f;
#pragma unroll 4
  for (int qq = 0; qq < nq; ++qq) {
    float4 f = F4[q0 + qq], dd = D4[q0 + qq];
    B = fmaf(dd.x, B, f.x); A *= dd.x;
    B = fmaf(dd.y, B, f.y); A *= dd.y;
    B = fmaf(dd.z, B, f.z); A *= dd.z;
    B = fmaf(dd.w, B, f.w); A *= dd.w;
  }
  // Inclusive composition scan across lanes
  for (int off = 1; off < 64; off <<= 1) {
    float Ao = __shfl_up(A, off, 64);
    float Bo = __shfl_up(B, off, 64);
    if (L >= off) { B = fmaf(A, Bo, B); A = A * Ao; }
  }
  float d = __shfl_up(B, 1, 64);  // d at my segment start
  if (L == 0) d = 0.f;
  // Phase 2: replay, emitting e_{j+1} = F0w[j] + Dw[j]*d_j
  // (entering element j: d == d_j; emit e BEFORE advancing d — order verified)
  if (L == 0) e[0] = 0.f;
#pragma unroll 4
  for (int qq = 0; qq < nq; ++qq) {
    float4 f = F4[q0 + qq], dd = D4[q0 + qq];
    float4 fw = Fw4[q0 + qq], dwv = Dw4[q0 + qq];
    int j = base + (qq << 2);
    if (j + 1 < DIM) e[j + 1] = fmaf(dwv.x, d, fw.x);
    d = fmaf(dd.x, d, f.x);
    if (j + 2 < DIM) e[j + 2] = fmaf(dwv.y, d, fw.y);
    d = fmaf(dd.y, d, f.y);
    if (j + 3 < DIM) e[j + 3] = fmaf(dwv.z, d, fw.z);
    d = fmaf(dd.z, d, f.z);
    if (j + 4 < DIM) e[j + 4] = fmaf(dwv.w, d, fw.w);
    d = fmaf(dd.w, d, f.w);
  }
}

// z[b,i] = leakyrelu(y*x[b,i] + e_i + b0); ld[b] = DIM*log|y| + cnt_neg*ln(alpha)
// x is read here for the LAST time (nontemporal load — should be an L3 hit from
// col_stats' pass); z is written once and never re-read (nontemporal store so it
// doesn't evict x ahead of the read frontier).
__global__ __launch_bounds__(256) void z_kernel(
    const float* __restrict__ x, const float* __restrict__ e,
    const float* __restrict__ yp, const float* __restrict__ bp,
    float* __restrict__ z, float* __restrict__ ld, int DIM) {
  const int row = blockIdx.x;
  const int tx = threadIdx.x;
  const float y = yp[0], b0 = bp[0];
  const nfloat4* xr = (const nfloat4*)(x + (size_t)row * DIM);
  const float4* er = (const float4*)e;
  nfloat4* zr = (nfloat4*)(z + (size_t)row * DIM);
  int cnt = 0;
  const int n4 = DIM >> 2;
  for (int k = tx; k < n4; k += blockDim.x) {
    nfloat4 xv = __builtin_nontemporal_load(&xr[k]);
    float4 ev = er[k];
    nfloat4 zv;
    float lin;
    lin = fmaf(y, xv.x, ev.x + b0); zv.x = lin >= 0.f ? lin : ALPHA * lin; cnt += (lin < 0.f);
    lin = fmaf(y, xv.y, ev.y + b0); zv.y = lin >= 0.f ? lin : ALPHA * lin; cnt += (lin < 0.f);
    lin = fmaf(y, xv.z, ev.z + b0); zv.z = lin >= 0.f ? lin : ALPHA * lin; cnt += (lin < 0.f);
    lin = fmaf(y, xv.w, ev.w + b0); zv.w = lin >= 0.f ? lin : ALPHA * lin; cnt += (lin < 0.f);
    __builtin_nontemporal_store(zv, &zr[k]);
  }
  for (int off = 32; off > 0; off >>= 1) cnt += __shfl_down(cnt, off, 64);
  __shared__ int wc[4];
  int wid = tx >> 6, lane = tx & 63;
  if (lane == 0) wc[wid] = cnt;
  __syncthreads();
  if (tx == 0) {
    int total = wc[0] + wc[1] + wc[2] + wc[3];
    ld[row] = (float)DIM * logf(fabsf(y)) + (float)total * LOG_ALPHA;
  }
}

extern "C" void kernel_launch(void* const* d_in, const int* in_sizes, int n_in,
                              void* d_out, int out_size, void* d_ws, size_t ws_size,
                              hipStream_t stream) {
  const float* x = (const float*)d_in[0];
  const float* y = (const float*)d_in[1];
  const float* w = (const float*)d_in[2];
  const float* b = (const float*)d_in[3];
  const float* u = (const float*)d_in[4];
  const float* v = (const float*)d_in[5];
  const float* a = (const float*)d_in[6];
  const int HID = in_sizes[2];         // w has HID elements
  const int DIM = in_sizes[0] / HID;   // x is [HID, DIM]

  const int RPB = 64;                  // rows per chunk: halves partials traffic
  const int NBY = HID / RPB;           // 128 row-chunks -> partials = 8 MB

  float* ws = (float*)d_ws;
  float* partials = ws;                              // NBY*4*DIM floats (8 MB)
  float* red = ws + (size_t)NBY * 4 * DIM;           // 4*DIM reduced stats
  float* F0v = red;           float* Dv = red + DIM;
  float* F0w = red + 2 * DIM; float* Dw = red + 3 * DIM;
  float* e = red + (size_t)4 * DIM;                  // DIM scan outputs

  float* z = (float*)d_out;
  float* ld = z + (size_t)HID * DIM;

  // Stage 1: partial stats, atomic-free (no zeroing needed — fully overwritten)
  dim3 grid1(DIM / (256 * 4), NBY);
  col_stats_kernel<<<grid1, 256, 0, stream>>>(x, w, v, u, a, partials, DIM, RPB);
  // Stage 2: fold partials -> F0v/Dv/F0w/Dw
  reduce_kernel<<<(4 * DIM) / 256, 256, 0, stream>>>(partials, red, DIM, NBY);
  // Stage 3: sequential affine scan (single wave)
  scan_kernel<<<1, 64, 0, stream>>>(F0v, Dv, F0w, Dw, e, DIM);
  // Stage 4: elementwise z + log-det count
  z_kernel<<<HID, 256, 0, stream>>>(x, e, y, b, z, ld, DIM);
}